// Round 2
// baseline (1398.560 us; speedup 1.0000x reference)
//
#include <hip/hip_runtime.h>
#include <math.h>

// ---------------- problem constants ----------------
#define N_DRUGS 4000
#define NN      8264            // total nodes
#define IN_DIM  1613
#define NRELS   4
#define DD1     1340
#define DD2     920
#define DD3     740
#define NEDGE   100000
#define NSEG    (NN * NRELS)    // 33056

// padded dims
#define MPAD    8320            // 65 * 128 (GEMM row tiles; rows >= NN are garbage-but-finite)
#define K1P     1632            // IN_DIM 1613 -> 51*32
#define K2P     1344            // DD1 1340 -> 42*32
#define K3P     928             // DD2 920  -> 29*32
#define N1PAD   1408            // DD1 -> 11*128
#define N2PAD   1024            // DD2 -> 8*128
#define N3PAD   768             // DD3 -> 6*128

typedef unsigned short u16;
typedef __attribute__((ext_vector_type(8))) short short8;
typedef __attribute__((ext_vector_type(4))) float floatx4;

__device__ __forceinline__ u16 f2bf(float f) {
  union { float f; unsigned u; } v; v.f = f;
  unsigned u = v.u + 0x7fffu + ((v.u >> 16) & 1u);   // RNE
  return (u16)(u >> 16);
}
__device__ __forceinline__ float bf2f(u16 h) {
  union { unsigned u; float f; } v; v.u = ((unsigned)h) << 16;
  return v.f;
}

// ---------------- small utility kernels ----------------
__global__ void k_zero_i32(int* p, int n) {
  int i = blockIdx.x * 256 + threadIdx.x;
  if (i < n) p[i] = 0;
}

__global__ void k_zero_u16v(u16* p, long long nvec) {  // zeros 8 u16 per thread
  long long i = (long long)blockIdx.x * 256 + threadIdx.x;
  if (i < nvec) {
    short8 z = {0,0,0,0,0,0,0,0};
    *((short8*)p + i) = z;
  }
}

__global__ void k_copy_i32(const int* a, int* b, int n) {
  int i = blockIdx.x * 256 + threadIdx.x;
  if (i < n) b[i] = a[i];
}

// ---------------- CSR build (counting sort by segment = dst*4 + rel) ------
__global__ void k_hist(const int* __restrict__ ei, const int* __restrict__ et,
                       int* __restrict__ counts) {
  int e = blockIdx.x * 256 + threadIdx.x;
  if (e < NEDGE) {
    int dst = ei[NEDGE + e];
    atomicAdd(&counts[dst * 4 + et[e]], 1);
  }
}

__global__ void k_scan(const int* __restrict__ counts, int* __restrict__ offsets) {
  __shared__ int part[1024];
  int tid = threadIdx.x;
  const int chunk = (NSEG + 1023) / 1024;  // 33
  int lo = tid * chunk, hi = min(lo + chunk, NSEG);
  int s = 0;
  for (int i = lo; i < hi; i++) s += counts[i];
  part[tid] = s;
  __syncthreads();
  for (int off = 1; off < 1024; off <<= 1) {
    int v = (tid >= off) ? part[tid - off] : 0;
    __syncthreads();
    part[tid] += v;
    __syncthreads();
  }
  int base = (tid == 0) ? 0 : part[tid - 1];
  for (int i = lo; i < hi; i++) { offsets[i] = base; base += counts[i]; }
  if (tid == 0) offsets[NSEG] = part[1023];
}

__global__ void k_fill(const int* __restrict__ ei, const int* __restrict__ et,
                       int* __restrict__ cursors, int* __restrict__ ssrc) {
  int e = blockIdx.x * 256 + threadIdx.x;
  if (e < NEDGE) {
    int src = ei[e], dst = ei[NEDGE + e];
    int pos = atomicAdd(&cursors[dst * 4 + et[e]], 1);
    if (pos < NEDGE) ssrc[pos] = src;
  }
}

// ---------------- feature builder: xf = concat(x, gene_emb) in bf16 -------
__global__ void k_build_xf(const float* __restrict__ x, const float* __restrict__ gene,
                           u16* __restrict__ xf) {
  int n = blockIdx.x;
  const float* srow = (n < N_DRUGS) ? (x + (long long)n * IN_DIM)
                                    : (gene + (long long)(n - N_DRUGS) * IN_DIM);
  u16* dst = xf + (long long)n * K1P;
  for (int f = threadIdx.x; f < K1P; f += 256)
    dst[f] = (f < IN_DIM) ? f2bf(srow[f]) : (u16)0;
}

// f32 (K x N, row-major) -> bf16 out[n][kofs+k], tiled transpose
__global__ void k_transpose(const float* __restrict__ in, int K, int N,
                            u16* __restrict__ out, int ldd, int kofs) {
  __shared__ float t[32][33];
  int k0 = blockIdx.x * 32, n0 = blockIdx.y * 32;
  int tx = threadIdx.x, ty = threadIdx.y;
  for (int i = ty; i < 32; i += 8) {
    int k = k0 + i, n = n0 + tx;
    t[i][tx] = (k < K && n < N) ? in[(long long)k * N + n] : 0.f;
  }
  __syncthreads();
  for (int i = ty; i < 32; i += 8) {
    int n = n0 + i, k = k0 + tx;
    if (n < N && k < K) out[(long long)n * ldd + kofs + k] = f2bf(t[tx][i]);
  }
}

// per-(node, rel r) mean over gathered T rows, accumulate into f32 HACC
__global__ void k_agg(const u16* __restrict__ T, int ldT,
                      float* __restrict__ HACC, int ldH, int F,
                      const int* __restrict__ offsets, const int* __restrict__ ssrc,
                      int r, int init) {
  int node = blockIdx.x;
  int seg = node * 4 + r;
  int beg = offsets[seg], end = offsets[seg + 1];
  float inv = (end > beg) ? 1.0f / (float)(end - beg) : 0.0f;
  float* o = HACC + (long long)node * ldH;
  for (int f = threadIdx.x; f < F; f += 256) {
    float acc = 0.f;
    for (int e = beg; e < end; e++)
      acc += bf2f(T[(long long)ssrc[e] * ldT + f]);
    acc *= inv;
    o[f] = init ? acc : (o[f] + acc);
  }
}

// ---------------- bf16 MFMA GEMM: C = act(A @ B^T + Cacc + bias) ----------
#define BM 128
#define BN 128
#define BK 32
#define LDT 40   // padded k-stride in LDS (80B rows: 16B-aligned, 2-way-max banks)

__global__ __launch_bounds__(256)
void k_gemm(const u16* __restrict__ A, int lda,
            const u16* __restrict__ B, int ldb, int ksteps,
            void* __restrict__ Cout, int ldc,
            const float* __restrict__ Cacc, int ldacc,
            int nreal, int nlimit, int mlimit,
            const float* __restrict__ bias, int relu, int f32out)
{
  __shared__ __align__(16) u16 At[BM * LDT];
  __shared__ __align__(16) u16 Bt[BN * LDT];
  int tid = threadIdx.x;
  int wave = tid >> 6, lane = tid & 63;
  int wm = (wave >> 1) << 6, wn = (wave & 1) << 6;
  int qd = lane >> 4, l16 = lane & 15;
  const u16* Ag = A + (long long)blockIdx.y * BM * lda;
  const u16* Bg = B + (long long)blockIdx.x * BN * ldb;
  int ar1 = tid >> 2, ak1 = (tid & 3) * 8;   // 512 chunks of 8 bf16

  floatx4 acc[4][4] = {};

  for (int ks = 0; ks < ksteps; ks++) {
    long long kb = (long long)ks * BK;
    __syncthreads();
    *(short8*)(At + ar1 * LDT + ak1)        = *(const short8*)(Ag + (long long)ar1 * lda + kb + ak1);
    *(short8*)(At + (ar1 + 64) * LDT + ak1) = *(const short8*)(Ag + (long long)(ar1 + 64) * lda + kb + ak1);
    *(short8*)(Bt + ar1 * LDT + ak1)        = *(const short8*)(Bg + (long long)ar1 * ldb + kb + ak1);
    *(short8*)(Bt + (ar1 + 64) * LDT + ak1) = *(const short8*)(Bg + (long long)(ar1 + 64) * ldb + kb + ak1);
    __syncthreads();
    short8 af[4], bfr[4];
#pragma unroll
    for (int i = 0; i < 4; i++)
      af[i] = *(const short8*)(At + (wm + i * 16 + l16) * LDT + qd * 8);
#pragma unroll
    for (int j = 0; j < 4; j++)
      bfr[j] = *(const short8*)(Bt + (wn + j * 16 + l16) * LDT + qd * 8);
#pragma unroll
    for (int i = 0; i < 4; i++)
#pragma unroll
      for (int j = 0; j < 4; j++)
        acc[i][j] = __builtin_amdgcn_mfma_f32_16x16x32_bf16(af[i], bfr[j], acc[i][j], 0, 0, 0);
  }

  // epilogue
#pragma unroll
  for (int i = 0; i < 4; i++) {
#pragma unroll
    for (int j = 0; j < 4; j++) {
      int col = blockIdx.x * BN + wn + j * 16 + l16;
      if (col >= nlimit) continue;
      float bv = (bias && col < nreal) ? bias[col] : 0.f;
#pragma unroll
      for (int rg = 0; rg < 4; rg++) {
        int row = blockIdx.y * BM + wm + i * 16 + qd * 4 + rg;
        if (row >= mlimit) continue;
        float v = 0.f;
        if (col < nreal) {
          v = acc[i][j][rg] + bv;
          if (Cacc) v += Cacc[(long long)row * ldacc + col];
          if (relu) v = fmaxf(v, 0.f);
        }
        if (f32out) ((float*)Cout)[(long long)row * ldc + col] = v;
        else        ((u16*)Cout)[(long long)row * ldc + col] = f2bf(v);
      }
    }
  }
}

// ---------------- final tiny layer: logits + log_softmax ----------------
__global__ void k_lin2(const float* __restrict__ emb, const float* __restrict__ w,
                       const float* __restrict__ b, float* __restrict__ out) {
  int node = blockIdx.x * 4 + (threadIdx.x >> 6);
  int lane = threadIdx.x & 63;
  if (node >= NN) return;
  const float* e = emb + (long long)node * DD3;
  float a0 = 0.f, a1 = 0.f;
  for (int f = lane; f < DD3; f += 64) {
    float v = e[f];
    a0 += v * w[2 * f];
    a1 += v * w[2 * f + 1];
  }
  for (int off = 32; off > 0; off >>= 1) {
    a0 += __shfl_down(a0, off);
    a1 += __shfl_down(a1, off);
  }
  if (lane == 0) {
    a0 += b[0]; a1 += b[1];
    float m = fmaxf(a0, a1);
    float ls = m + logf(expf(a0 - m) + expf(a1 - m));
    out[(long long)node * 2]     = a0 - ls;
    out[(long long)node * 2 + 1] = a1 - ls;
  }
}

// ---------------- launch ----------------
extern "C" void kernel_launch(void* const* d_in, const int* in_sizes, int n_in,
                              void* d_out, int out_size, void* d_ws, size_t ws_size,
                              hipStream_t stream)
{
  const float* x      = (const float*)d_in[0];
  const float* gene   = (const float*)d_in[1];
  const float* w_rel1 = (const float*)d_in[2];
  const float* root1  = (const float*)d_in[3];
  const float* b1     = (const float*)d_in[4];
  const float* w_rel2 = (const float*)d_in[5];
  const float* root2  = (const float*)d_in[6];
  const float* b2     = (const float*)d_in[7];
  const float* lin1_w = (const float*)d_in[8];
  const float* lin1_b = (const float*)d_in[9];
  const float* lin2_w = (const float*)d_in[10];
  const float* lin2_b = (const float*)d_in[11];
  const int*   ei     = (const int*)d_in[12];
  const int*   et     = (const int*)d_in[13];
  float* out = (float*)d_out;

  // workspace layout (~155.6 MB total)
  char* ws = (char*)d_ws;
  size_t off = 0;
  auto alloc = [&](size_t bytes) -> void* {
    void* p = ws + off;
    off += (bytes + 255) & ~(size_t)255;
    return p;
  };
  const size_t W1SLOT = (size_t)N1PAD * K1P;   // per-relation weight slot (elems)
  const size_t W2SLOT = (size_t)N2PAD * K2P;
  u16* XF   = (u16*)alloc((size_t)MPAD * K1P * 2);   // also reused as H2 (MPAD x K3P)
  u16* T    = (u16*)alloc((size_t)MPAD * K2P * 2);   // per-relation transform output
  float* HACC = (float*)alloc((size_t)MPAD * K2P * 4);
  u16* H1   = (u16*)alloc((size_t)MPAD * K2P * 2);
  u16* W1T  = (u16*)alloc(5 * W1SLOT * 2);           // r0..r3, root
  u16* W2T  = (u16*)alloc(5 * W2SLOT * 2);
  u16* W3T  = (u16*)alloc((size_t)N3PAD * K3P * 2);
  int* counts  = (int*)alloc((NSEG + 1) * 4);
  int* offsets = (int*)alloc((NSEG + 1) * 4);
  int* cursors = (int*)alloc((size_t)NSEG * 4);
  int* ssrc    = (int*)alloc((size_t)NEDGE * 4);
  u16* H2 = XF;                                      // alias: XF dead after layer-1 root GEMM
  float* emb = out + 2 * NN;   // d_out = [log_softmax 8264x2][emb 8264x740]

  if (off > ws_size) return;   // diagnostic: stub-like absmax instead of GPU fault

  // ---- CSR build ----
  k_zero_i32<<<(NSEG + 1 + 255) / 256, 256, 0, stream>>>(counts, NSEG + 1);
  k_hist<<<(NEDGE + 255) / 256, 256, 0, stream>>>(ei, et, counts);
  k_scan<<<1, 1024, 0, stream>>>(counts, offsets);
  k_copy_i32<<<(NSEG + 255) / 256, 256, 0, stream>>>(offsets, cursors, NSEG);
  k_fill<<<(NEDGE + 255) / 256, 256, 0, stream>>>(ei, et, cursors, ssrc);

  // ---- weights: zero pads then transpose into bf16 N x K slots ----
  long long wvec = (5LL * W1SLOT + 5LL * W2SLOT + (long long)N3PAD * K3P) / 8;
  k_zero_u16v<<<(unsigned)((wvec + 255) / 256), 256, 0, stream>>>(W1T, wvec);
  dim3 tb(32, 8);
  for (int r = 0; r < 4; r++)
    k_transpose<<<dim3((IN_DIM + 31) / 32, (DD1 + 31) / 32), tb, 0, stream>>>(
        w_rel1 + (long long)r * IN_DIM * DD1, IN_DIM, DD1, W1T + r * W1SLOT, K1P, 0);
  k_transpose<<<dim3((IN_DIM + 31) / 32, (DD1 + 31) / 32), tb, 0, stream>>>(
      root1, IN_DIM, DD1, W1T + 4 * W1SLOT, K1P, 0);
  for (int r = 0; r < 4; r++)
    k_transpose<<<dim3((DD1 + 31) / 32, (DD2 + 31) / 32), tb, 0, stream>>>(
        w_rel2 + (long long)r * DD1 * DD2, DD1, DD2, W2T + r * W2SLOT, K2P, 0);
  k_transpose<<<dim3((DD1 + 31) / 32, (DD2 + 31) / 32), tb, 0, stream>>>(
      root2, DD1, DD2, W2T + 4 * W2SLOT, K2P, 0);
  k_transpose<<<dim3((DD2 + 31) / 32, (DD3 + 31) / 32), tb, 0, stream>>>(
      lin1_w, DD2, DD3, W3T, K3P, 0);

  // ---- input features ----
  k_build_xf<<<NN, 256, 0, stream>>>(x, gene, XF);

  // ---- layer 1: per-relation transform + mean-aggregate, then root ----
  for (int r = 0; r < 4; r++) {
    k_gemm<<<dim3(N1PAD / 128, MPAD / 128), 256, 0, stream>>>(
        XF, K1P, W1T + r * W1SLOT, K1P, K1P / 32,
        T, K2P, (const float*)nullptr, 0, K2P, K2P, MPAD,
        (const float*)nullptr, 0, 0);
    k_agg<<<NN, 256, 0, stream>>>(T, K2P, HACC, K2P, DD1, offsets, ssrc, r, r == 0);
  }
  k_gemm<<<dim3(N1PAD / 128, MPAD / 128), 256, 0, stream>>>(
      XF, K1P, W1T + 4 * W1SLOT, K1P, K1P / 32,
      H1, K2P, HACC, K2P, DD1, K2P, MPAD, b1, 1, 0);

  // ---- layer 2 ----
  for (int r = 0; r < 4; r++) {
    k_gemm<<<dim3(N2PAD / 128, MPAD / 128), 256, 0, stream>>>(
        H1, K2P, W2T + r * W2SLOT, K2P, K2P / 32,
        T, K3P, (const float*)nullptr, 0, K3P, K3P, MPAD,
        (const float*)nullptr, 0, 0);
    k_agg<<<NN, 256, 0, stream>>>(T, K3P, HACC, K3P, DD2, offsets, ssrc, r, r == 0);
  }
  k_gemm<<<dim3(N2PAD / 128, MPAD / 128), 256, 0, stream>>>(
      H1, K2P, W2T + 4 * W2SLOT, K2P, K2P / 32,
      H2, K3P, HACC, K3P, DD2, K3P, MPAD, b2, 1, 0);

  // ---- lin1 -> emb (f32, straight into d_out) ----
  k_gemm<<<dim3(N3PAD / 128, MPAD / 128), 256, 0, stream>>>(
      H2, K3P, W3T, K3P, K3P / 32,
      emb, DD3, (const float*)nullptr, 0, DD3, DD3, NN, lin1_b, 1, 1);

  // ---- lin2 + log_softmax ----
  k_lin2<<<(NN + 3) / 4, 256, 0, stream>>>(emb, lin2_w, lin2_b, out);
}